// Round 16
// baseline (93.583 us; speedup 1.0000x reference)
//
#include <hip/hip_runtime.h>
#include <hip/hip_bf16.h>
#include <stdint.h>

typedef __bf16 bf16;
typedef __bf16 bf16x4 __attribute__((ext_vector_type(4)));
typedef __bf16 bf16x8 __attribute__((ext_vector_type(8)));
typedef float f32x4 __attribute__((ext_vector_type(4)));

__device__ __forceinline__ f32x4 mfma16(bf16x8 a, bf16x8 b, f32x4 c) {
    return __builtin_amdgcn_mfma_f32_16x16x32_bf16(a, b, c, 0, 0, 0);
}

__device__ __forceinline__ void gload_lds16(const void* g, void* l) {
    __builtin_amdgcn_global_load_lds((__attribute__((address_space(1))) void*)g,
                                     (__attribute__((address_space(3))) void*)l,
                                     16, 0, 0);
}

// ---------------- fused cast fp32 -> bf16 for all three inputs ----------------
__global__ void k_cast3(const float* __restrict__ x, const float* __restrict__ wa,
                        const float* __restrict__ wp, bf16* __restrict__ xb,
                        bf16* __restrict__ wab, bf16* __restrict__ wpb) {
    const int N1 = 786432, N2 = 442368, N3 = 147456;  // float4 chunks
    int i = blockIdx.x * blockDim.x + threadIdx.x;
    int stride = gridDim.x * blockDim.x;
    for (; i < N1 + N2 + N3; i += stride) {
        const float* src; bf16* dst; int j = i;
        if (j < N1)           { src = x;  dst = xb; }
        else if (j < N1 + N2) { src = wa; dst = wab; j -= N1; }
        else                  { src = wp; dst = wpb; j -= N1 + N2; }
        float4 v = reinterpret_cast<const float4*>(src)[j];
        bf16x4 o = { (bf16)v.x, (bf16)v.y, (bf16)v.z, (bf16)v.w };
        reinterpret_cast<bf16x4*>(dst)[j] = o;
    }
}

// ---------------- GEMM: C[M,N] = A[M,K] * W[N,K]^T + bias ----------------
// BM=128, BK=64, BN templated. XOR-swizzled LDS; bijective XCD chunking (R13).
// FUSEV (gemm1 only): CTAs with bn>=1536 write their C-tile TRANSPOSED into
// vT[bh][d][t] via 4 quarter-passes through a reused-As Lt[64][68] buffer
// (R15 bug: t-extent 128 overflowed a 70-wide row; quarters keep indices <64).
template<int BN, bool BF16_OUT, bool FUSEV>
__global__ __launch_bounds__(256) void k_gemm_bt(
        const bf16* __restrict__ A, const bf16* __restrict__ W,
        const float* __restrict__ bias, void* __restrict__ Cout,
        bf16* __restrict__ vTout, int M, int N, int K) {
    constexpr int FN = BN / 32;          // wf frags per wave (4 or 2)
    __shared__ bf16 As[128 * 64];
    __shared__ bf16 Ws[BN * 64];
    const int tid = threadIdx.x;
    const int l = tid & 63, w = tid >> 6;
    const int lr = l & 15, lq = l >> 4;
    const int wm = w >> 1, wn = w & 1;

    const int nwg = gridDim.x;
    const int q8 = nwg >> 3;                       // grid multiple of 8
    const int swz = (blockIdx.x & 7) * q8 + (blockIdx.x >> 3);
    const int nbx = N / BN;
    const int bm = (swz / nbx) * 128, bn = (swz % nbx) * BN;

    f32x4 acc[4][FN] = {};

    for (int k0 = 0; k0 < K; k0 += 64) {
        __syncthreads();
        #pragma unroll
        for (int i = 0; i < 4; ++i) {
            int c = tid + i * 256;
            int row = c >> 3, j = c & 7;
            int src8 = (j ^ (row & 7)) * 8;
            gload_lds16(A + (size_t)(bm + row) * K + k0 + src8, As + c * 8);
        }
        #pragma unroll
        for (int i = 0; i < FN; ++i) {
            int c = tid + i * 256;
            int row = c >> 3, j = c & 7;
            int src8 = (j ^ (row & 7)) * 8;
            gload_lds16(W + (size_t)(bn + row) * K + k0 + src8, Ws + c * 8);
        }
        __syncthreads();
        bf16x8 af[2][4], wf[2][FN];
        #pragma unroll
        for (int ks = 0; ks < 2; ++ks) {
            #pragma unroll
            for (int f = 0; f < 4; ++f) {
                int ra = wm * 64 + f * 16 + lr;
                af[ks][f] = *reinterpret_cast<const bf16x8*>(
                    As + ra * 64 + (((ks * 4 + lq) ^ (lr & 7)) * 8));
            }
            #pragma unroll
            for (int f = 0; f < FN; ++f) {
                int rb = wn * (FN * 16) + f * 16 + lr;
                wf[ks][f] = *reinterpret_cast<const bf16x8*>(
                    Ws + rb * 64 + (((ks * 4 + lq) ^ (lr & 7)) * 8));
            }
        }
        #pragma unroll
        for (int ks = 0; ks < 2; ++ks)
            #pragma unroll
            for (int fm = 0; fm < 4; ++fm)
                #pragma unroll
                for (int fn = 0; fn < FN; ++fn)
                    acc[fm][fn] = mfma16(af[ks][fm], wf[ks][fn], acc[fm][fn]);
    }

    if (FUSEV && bn >= 1536) {
        // ---- fused V-transpose epilogue: 4 quarter-passes (hh = head, th = t-half)
        auto Lt = reinterpret_cast<bf16(*)[68]>(As);   // 64 x 68 x 2B = 8704 B <= As
        const int bq = bm >> 11, t0 = bm & 2047;
        const int h0 = (bn - 1536) >> 6;
        #pragma unroll
        for (int hh = 0; hh < 2; ++hh) {
            #pragma unroll
            for (int th = 0; th < 2; ++th) {
                __syncthreads();   // prior LDS use done
                if (wn == hh && wm == th) {
                    // this wave's 64x64 quarter: local t = fm*16+lq*4+r, d = fn*16+lr
                    #pragma unroll
                    for (int fm = 0; fm < 4; ++fm)
                        #pragma unroll
                        for (int fn = 0; fn < FN; ++fn) {
                            float bv = bias[bn + hh * 64 + fn * 16 + lr];
                            bf16x4 v4 = { (bf16)(acc[fm][fn][0] + bv),
                                          (bf16)(acc[fm][fn][1] + bv),
                                          (bf16)(acc[fm][fn][2] + bv),
                                          (bf16)(acc[fm][fn][3] + bv) };
                            *reinterpret_cast<bf16x4*>(
                                &Lt[fn * 16 + lr][fm * 16 + lq * 4]) = v4;
                        }
                }
                __syncthreads();
                // readout: thread -> (d = tid>>2, tc = tid&3), 16 bf16 along t
                const int d = tid >> 2, tc = tid & 3;
                bf16* dst = vTout + (size_t)(bq * 12 + h0 + hh) * 131072
                            + (size_t)d * 2048 + t0 + th * 64 + tc * 16;
                *reinterpret_cast<bf16x8*>(dst) =
                    *reinterpret_cast<const bf16x8*>(&Lt[d][tc * 16]);
                *reinterpret_cast<bf16x8*>(dst + 8) =
                    *reinterpret_cast<const bf16x8*>(&Lt[d][tc * 16 + 8]);
            }
        }
        return;
    }

    #pragma unroll
    for (int fm = 0; fm < 4; ++fm) {
        #pragma unroll
        for (int fn = 0; fn < FN; ++fn) {
            int row = bm + wm * 64 + fm * 16 + lq * 4;
            int col = bn + wn * (FN * 16) + fn * 16 + lr;
            float bv = bias[col];
            #pragma unroll
            for (int r = 0; r < 4; ++r) {
                float v = acc[fm][fn][r] + bv;
                if (BF16_OUT)
                    ((bf16*)Cout)[(size_t)(row + r) * N + col] = (bf16)v;
                else
                    ((float*)Cout)[(size_t)(row + r) * N + col] = v;
            }
        }
    }
}

// ---------------- causal flash attention (R14: kv-split across waves) ---------
// Wave w = (qh = w>>1, hv = w&1): q-half qh (32 rows), kv-half hv (32 of 64).
// K: 3-buffer 2-ahead; V: 2-buffer 1-ahead; steady vmcnt(2); LDS 40KB, 4/CU.
#define CLOG2E 1.02014439f   // (1/sqrt(2)) * log2(e)

__global__ __launch_bounds__(256, 4) void k_flash_attn(
        const bf16* __restrict__ qkv, const bf16* __restrict__ vT,
        bf16* __restrict__ att, float* __restrict__ part, int mode) {
    __shared__ bf16 Ks[3][4096];   // [kv][d], chunk j of row holds src chunk j^(row&7)
    __shared__ bf16 VTs[2][4096];  // [d][kv], same swizzle

    const int tid = threadIdx.x;
    const int l = tid & 63, w = tid >> 6;
    const int lr = l & 15, lq = l >> 4;
    const int qh = w >> 1, hv = w & 1;

    const int bid = blockIdx.x;
    int qb, h, b, jt0, jt1, slot;
    bool dopart;
    if (mode) {
        int bh = bid % 24, idx = bid / 24;
        h = bh % 12; b = bh / 12;
        if (idx < 16)      { qb = 16 + idx;  jt0 = 0;  jt1 = 16;     dopart = true;  slot = (bh * 16 + idx) * 2; }
        else if (idx < 32) { qb = 47 - idx;  jt0 = 16; jt1 = qb + 1; dopart = true;  slot = (bh * 16 + (qb - 16)) * 2 + 1; }
        else               { qb = 47 - idx;  jt0 = 0;  jt1 = qb + 1; dopart = false; slot = 0; }
    } else {
        const int s = bid >> 8, i = (bid >> 3) & 31, t7 = bid & 7;
        if (s == 0)      qb = i;
        else if (s == 2) qb = (i + 16) & 31;
        else             qb = (i < 8) ? (31 - 2 * i) : (i < 16) ? (30 - 2 * i)
                           : (i < 24) ? (62 - 2 * i) : (63 - 2 * i);
        const int hb = s * 8 + t7;
        h = hb % 12; b = hb / 12;
        jt0 = 0; jt1 = qb + 1; dopart = false; slot = 0;
    }

    const bf16* Qp  = qkv + (size_t)b * 2048 * 2304 + h * 64;
    const bf16* Kp  = Qp + 768;
    const bf16* Vtp = vT + (size_t)(b * 12 + h) * 64 * 2048;  // [d][t]

    // Q rows for this wave: qb*64 + qh*32 + qg*16 + lr
    bf16x8 qf[2][2];
    #pragma unroll
    for (int qg = 0; qg < 2; ++qg)
        #pragma unroll
        for (int ks = 0; ks < 2; ++ks)
            qf[qg][ks] = *reinterpret_cast<const bf16x8*>(
                Qp + (size_t)(qb * 64 + qh * 32 + qg * 16 + lr) * 2304 + ks * 32 + lq * 8);

    f32x4 o[2][4] = {};
    float lsum0 = 0.f, lsum1 = 0.f;

    auto stageK = [&](int buf, int kv0) {
        #pragma unroll
        for (int ii = 0; ii < 2; ++ii) {
            int c = tid + ii * 256;
            int row = c >> 3, j = c & 7;
            gload_lds16(Kp + (size_t)(kv0 + row) * 2304 + ((j ^ (row & 7)) * 8),
                        &Ks[buf][c * 8]);
        }
    };
    auto stageV = [&](int buf, int kv0) {
        #pragma unroll
        for (int ii = 0; ii < 2; ++ii) {
            int c = tid + ii * 256;
            int row = c >> 3, j = c & 7;       // row = d, chunks along kv
            gload_lds16(Vtp + (size_t)row * 2048 + kv0 + ((j ^ (row & 7)) * 8),
                        &VTs[buf][c * 8]);
        }
    };

    // prologue: K(0), V(0), K(1); wait K0+V0 (leave K1 in flight)
    stageK(0, jt0 * 64);
    stageV(0, jt0 * 64);
    const bool two = (jt1 > jt0 + 1);
    if (two) stageK(1, jt0 * 64 + 64);
    if (two) asm volatile("s_waitcnt vmcnt(2)" ::: "memory");
    else     asm volatile("s_waitcnt vmcnt(0)" ::: "memory");
    __builtin_amdgcn_s_barrier();
    asm volatile("" ::: "memory");

    const int rsw = lr & 7;

    for (int jt = jt0; jt < jt1; ++jt) {
        const int curK = (jt - jt0) % 3;
        const int curV = (jt - jt0) & 1;
        const int kv0 = jt * 64;
        if (jt + 1 < jt1) stageV(curV ^ 1, kv0 + 64);            // V: 1-ahead
        if (jt + 2 < jt1) stageK((jt + 2 - jt0) % 3, kv0 + 128); // K: 2-ahead

        const bool diag = (jt == qb);
        float p[2][2][4];   // [t'][qg][r]; kv = hv*32 + t'*16 + lq*4 + r; q col = lr
        __builtin_amdgcn_s_setprio(1);
        #pragma unroll
        for (int tp = 0; tp < 2; ++tp) {
            const int row = hv * 32 + tp * 16 + lr;
            bf16x8 kf0 = *reinterpret_cast<const bf16x8*>(
                &Ks[curK][row * 64 + ((lq ^ rsw) * 8)]);
            bf16x8 kf1 = *reinterpret_cast<const bf16x8*>(
                &Ks[curK][row * 64 + (((4 + lq) ^ rsw) * 8)]);
            #pragma unroll
            for (int qg = 0; qg < 2; ++qg) {
                f32x4 s = {0.f, 0.f, 0.f, 0.f};
                s = mfma16(kf0, qf[qg][0], s);
                s = mfma16(kf1, qf[qg][1], s);
                #pragma unroll
                for (int r = 0; r < 4; ++r)
                    p[tp][qg][r] = __builtin_amdgcn_exp2f(s[r] * CLOG2E);
            }
        }
        __builtin_amdgcn_s_setprio(0);
        if (diag) {            // wave-uniform: mask only on the diagonal tile
            #pragma unroll
            for (int tp = 0; tp < 2; ++tp)
                #pragma unroll
                for (int qg = 0; qg < 2; ++qg)
                    #pragma unroll
                    for (int r = 0; r < 4; ++r)
                        if (hv * 32 + tp * 16 + lq * 4 + r > qh * 32 + qg * 16 + lr)
                            p[tp][qg][r] = 0.f;
        }
        {   // tree-reduced tile sums per q-group
            float a0 = (p[0][0][0] + p[0][0][1]) + (p[0][0][2] + p[0][0][3]);
            float a1 = (p[1][0][0] + p[1][0][1]) + (p[1][0][2] + p[1][0][3]);
            lsum0 += a0 + a1;
            float b0 = (p[0][1][0] + p[0][1][1]) + (p[0][1][2] + p[0][1][3]);
            float b1 = (p[1][1][0] + p[1][1][1]) + (p[1][1][2] + p[1][1][3]);
            lsum1 += b0 + b1;
        }

        // T12 relabeled: per qg, p[t'][qg][*] -> pa[qg] = P[q=lr][kv_local=lq*8+e]
        bf16x8 pa[2];
        #pragma unroll
        for (int qg = 0; qg < 2; ++qg) {
            unsigned A0, B0, A1, B1;
            asm("v_cvt_pk_bf16_f32 %0, %1, %2" : "=v"(A0) : "v"(p[0][qg][0]), "v"(p[0][qg][1]));
            asm("v_cvt_pk_bf16_f32 %0, %1, %2" : "=v"(A1) : "v"(p[0][qg][2]), "v"(p[0][qg][3]));
            asm("v_cvt_pk_bf16_f32 %0, %1, %2" : "=v"(B0) : "v"(p[1][qg][0]), "v"(p[1][qg][1]));
            asm("v_cvt_pk_bf16_f32 %0, %1, %2" : "=v"(B1) : "v"(p[1][qg][2]), "v"(p[1][qg][3]));
            asm volatile("v_permlane32_swap_b32 %0, %1" : "+v"(A0), "+v"(B0));
            asm volatile("v_permlane16_swap_b32 %0, %1" : "+v"(A0), "+v"(B0));
            asm volatile("v_permlane32_swap_b32 %0, %1" : "+v"(A1), "+v"(B1));
            asm volatile("v_permlane16_swap_b32 %0, %1" : "+v"(A1), "+v"(B1));
            union { unsigned u[4]; bf16x8 v8; } pk_;
            pk_.u[0] = A0; pk_.u[1] = A1; pk_.u[2] = B0; pk_.u[3] = B1;
            pa[qg] = pk_.v8;
        }

        __builtin_amdgcn_s_setprio(1);
        #pragma unroll
        for (int db = 0; db < 4; ++db) {
            const int row = db * 16 + lr;
            bf16x8 vf = *reinterpret_cast<const bf16x8*>(
                &VTs[curV][row * 64 + (((hv * 4 + lq) ^ rsw) * 8)]);
            o[0][db] = mfma16(pa[0], vf, o[0][db]);
            o[1][db] = mfma16(pa[1], vf, o[1][db]);
        }
        __builtin_amdgcn_s_setprio(0);

        // counted wait: K(j+1)+V(j+1) complete; K(j+2) stays in flight
        if (jt + 1 < jt1) {
            if (jt + 2 < jt1) asm volatile("s_waitcnt vmcnt(2)" ::: "memory");
            else              asm volatile("s_waitcnt vmcnt(0)" ::: "memory");
        }
        __builtin_amdgcn_s_barrier();
        asm volatile("" ::: "memory");
    }

    // wave-level row sums (over this wave's kv-half) across the 4 lq groups
    lsum0 += __shfl_xor(lsum0, 16); lsum0 += __shfl_xor(lsum0, 32);
    lsum1 += __shfl_xor(lsum1, 16); lsum1 += __shfl_xor(lsum1, 32);

    // cross-pair combine via reused Ks LDS: hv=1 writes, hv=0 adds + stores.
    {
        float* xf = (float*)&Ks[0][0];     // 2 regions x 64 lanes x 34 f32 = 17408 B
        float* rg = xf + (size_t)(qh * 64 + l) * 34;
        if (hv == 1) {
            #pragma unroll
            for (int qg = 0; qg < 2; ++qg)
                #pragma unroll
                for (int db = 0; db < 4; ++db)
                    #pragma unroll
                    for (int r = 0; r < 4; ++r)
                        rg[qg * 16 + db * 4 + r] = o[qg][db][r];
            rg[32] = lsum0; rg[33] = lsum1;
        }
        __syncthreads();
        if (hv == 0) {
            #pragma unroll
            for (int qg = 0; qg < 2; ++qg)
                #pragma unroll
                for (int db = 0; db < 4; ++db)
                    #pragma unroll
                    for (int r = 0; r < 4; ++r)
                        o[qg][db][r] += rg[qg * 16 + db * 4 + r];
            lsum0 += rg[32]; lsum1 += rg[33];

            if (dopart) {
                float* pb = part + (size_t)slot * 4160;
                #pragma unroll
                for (int qg = 0; qg < 2; ++qg) {
                    #pragma unroll
                    for (int db = 0; db < 4; ++db)
                        #pragma unroll
                        for (int r = 0; r < 4; ++r)
                            pb[(qh * 32 + qg * 16 + lq * 4 + r) * 64 + db * 16 + lr] = o[qg][db][r];
                }
                if (lq == 0) {
                    pb[4096 + qh * 32 + lr]      = lsum0;
                    pb[4096 + qh * 32 + 16 + lr] = lsum1;
                }
            } else {
                float inv0[4], inv1[4];
                #pragma unroll
                for (int r = 0; r < 4; ++r) {
                    inv0[r] = 1.0f / __shfl(lsum0, lq * 4 + r);
                    inv1[r] = 1.0f / __shfl(lsum1, lq * 4 + r);
                }
                #pragma unroll
                for (int db = 0; db < 4; ++db)
                    #pragma unroll
                    for (int r = 0; r < 4; ++r) {
                        int q0 = qb * 64 + qh * 32 + lq * 4 + r;
                        att[(size_t)(b * 2048 + q0) * 768 + h * 64 + db * 16 + lr] =
                            (bf16)(o[0][db][r] * inv0[r]);
                        att[(size_t)(b * 2048 + q0 + 16) * 768 + h * 64 + db * 16 + lr] =
                            (bf16)(o[1][db][r] * inv1[r]);
                    }
            }
        }
    }
}

// ---------------- combine split-KV partials ----------------
__global__ __launch_bounds__(256) void k_attn_reduce(
        const float* __restrict__ part, bf16* __restrict__ att) {
    int g = blockIdx.x;                 // 384 = 24 bh * 16 qb
    int bh = g / 16, q16 = g % 16, qb = 16 + q16;
    int h = bh % 12, b = bh / 12;
    const float* p0 = part + (size_t)((bh * 16 + q16) * 2) * 4160;
    const float* p1 = p0 + 4160;
    for (int e = threadIdx.x; e < 4096; e += 256) {
        int row = e >> 6, col = e & 63;
        float O = p0[e] + p1[e];
        float L = p0[4096 + row] + p1[4096 + row];
        att[(size_t)(b * 2048 + qb * 64 + row) * 768 + h * 64 + col] = (bf16)(O / L);
    }
}

// ---------------- launch ----------------
extern "C" void kernel_launch(void* const* d_in, const int* in_sizes, int n_in,
                              void* d_out, int out_size, void* d_ws, size_t ws_size,
                              hipStream_t stream) {
    const float* x      = (const float*)d_in[0];
    const float* w_attn = (const float*)d_in[1];
    const float* b_attn = (const float*)d_in[2];
    const float* w_proj = (const float*)d_in[3];
    const float* b_proj = (const float*)d_in[4];

    char* ws = (char*)d_ws;
    // Lifetimes: xb (cast3->gemm1) overlaps att (attn->gemm2); vT written by
    // gemm1 epilogue (while gemm1 reads xb@0 -> disjoint), read by attn.
    bf16* xb   = (bf16*)(ws + 0);          // 4096x768   = 6291456 B (dead after gemm1)
    bf16* att  = (bf16*)(ws + 0);          // 4096x768   (after gemm1; overlaps xb)
    bf16* wab  = (bf16*)(ws + 6291456);    // 2304x768   = 3538944 B
    bf16* wpb  = (bf16*)(ws + 9830400);    //  768x768   = 1179648 B
    bf16* qkv  = (bf16*)(ws + 11010048);   // 4096x2304  = 18874368 B (V-third unused)
    bf16* vT   = (bf16*)(ws + 29884416);   // 24x64x2048 = 6291456 B
    float* part = (float*)(ws + 36175872); // 768 slots x 4160 f32 = 12779520 B
    const unsigned long long WS_NEEDED = 36175872ull + 12779520ull;  // proven available (R5)

    k_cast3<<<2048, 256, 0, stream>>>(x, w_attn, w_proj, xb, wab, wpb);

    // gemm1: 576 CTAs (576 % 8 == 0 -> bijective XCD swizzle), fused V-transpose
    k_gemm_bt<128, true, true><<<576, 256, 0, stream>>>(
        xb, wab, b_attn, qkv, vT, 4096, 2304, 768);

    if (ws_size >= WS_NEEDED) {
        k_flash_attn<<<1152, 256, 0, stream>>>(qkv, vT, att, part, 1);
        k_attn_reduce<<<384, 256, 0, stream>>>(part, att);
    } else {
        k_flash_attn<<<768, 256, 0, stream>>>(qkv, vT, att, part, 0);
    }

    // gemm2: 384 CTAs (384 % 8 == 0)
    k_gemm_bt<64, false, false><<<384, 256, 0, stream>>>(
        att, wpb, b_proj, d_out, nullptr, 4096, 768, 768);
}

// Round 17
// 84.935 us; speedup vs baseline: 1.1018x; 1.1018x over previous
//
#include <hip/hip_runtime.h>
#include <hip/hip_bf16.h>
#include <stdint.h>

typedef __bf16 bf16;
typedef __bf16 bf16x4 __attribute__((ext_vector_type(4)));
typedef __bf16 bf16x8 __attribute__((ext_vector_type(8)));
typedef float f32x4 __attribute__((ext_vector_type(4)));

__device__ __forceinline__ f32x4 mfma16(bf16x8 a, bf16x8 b, f32x4 c) {
    return __builtin_amdgcn_mfma_f32_16x16x32_bf16(a, b, c, 0, 0, 0);
}

__device__ __forceinline__ void gload_lds16(const void* g, void* l) {
    __builtin_amdgcn_global_load_lds((__attribute__((address_space(1))) void*)g,
                                     (__attribute__((address_space(3))) void*)l,
                                     16, 0, 0);
}

// ---------------- fused cast fp32 -> bf16 for all three inputs ----------------
__global__ void k_cast3(const float* __restrict__ x, const float* __restrict__ wa,
                        const float* __restrict__ wp, bf16* __restrict__ xb,
                        bf16* __restrict__ wab, bf16* __restrict__ wpb) {
    const int N1 = 786432, N2 = 442368, N3 = 147456;  // float4 chunks
    int i = blockIdx.x * blockDim.x + threadIdx.x;
    int stride = gridDim.x * blockDim.x;
    for (; i < N1 + N2 + N3; i += stride) {
        const float* src; bf16* dst; int j = i;
        if (j < N1)           { src = x;  dst = xb; }
        else if (j < N1 + N2) { src = wa; dst = wab; j -= N1; }
        else                  { src = wp; dst = wpb; j -= N1 + N2; }
        float4 v = reinterpret_cast<const float4*>(src)[j];
        bf16x4 o = { (bf16)v.x, (bf16)v.y, (bf16)v.z, (bf16)v.w };
        reinterpret_cast<bf16x4*>(dst)[j] = o;
    }
}

// ---------------- GEMM: C[M,N] = A[M,K] * W[N,K]^T + bias ----------------
// BM=128, BK=64, BN templated. XOR-swizzled LDS; bijective XCD chunking (R13).
template<int BN, bool BF16_OUT>
__global__ __launch_bounds__(256) void k_gemm_bt(
        const bf16* __restrict__ A, const bf16* __restrict__ W,
        const float* __restrict__ bias, void* __restrict__ Cout,
        int M, int N, int K) {
    constexpr int FN = BN / 32;          // wf frags per wave (4 or 2)
    __shared__ bf16 As[128 * 64];
    __shared__ bf16 Ws[BN * 64];
    const int tid = threadIdx.x;
    const int l = tid & 63, w = tid >> 6;
    const int lr = l & 15, lq = l >> 4;
    const int wm = w >> 1, wn = w & 1;

    const int nwg = gridDim.x;
    const int q8 = nwg >> 3;                       // grid multiple of 8
    const int swz = (blockIdx.x & 7) * q8 + (blockIdx.x >> 3);
    const int nbx = N / BN;
    const int bm = (swz / nbx) * 128, bn = (swz % nbx) * BN;

    f32x4 acc[4][FN] = {};

    for (int k0 = 0; k0 < K; k0 += 64) {
        __syncthreads();
        #pragma unroll
        for (int i = 0; i < 4; ++i) {
            int c = tid + i * 256;
            int row = c >> 3, j = c & 7;
            int src8 = (j ^ (row & 7)) * 8;
            gload_lds16(A + (size_t)(bm + row) * K + k0 + src8, As + c * 8);
        }
        #pragma unroll
        for (int i = 0; i < FN; ++i) {
            int c = tid + i * 256;
            int row = c >> 3, j = c & 7;
            int src8 = (j ^ (row & 7)) * 8;
            gload_lds16(W + (size_t)(bn + row) * K + k0 + src8, Ws + c * 8);
        }
        __syncthreads();
        bf16x8 af[2][4], wf[2][FN];
        #pragma unroll
        for (int ks = 0; ks < 2; ++ks) {
            #pragma unroll
            for (int f = 0; f < 4; ++f) {
                int ra = wm * 64 + f * 16 + lr;
                af[ks][f] = *reinterpret_cast<const bf16x8*>(
                    As + ra * 64 + (((ks * 4 + lq) ^ (lr & 7)) * 8));
            }
            #pragma unroll
            for (int f = 0; f < FN; ++f) {
                int rb = wn * (FN * 16) + f * 16 + lr;
                wf[ks][f] = *reinterpret_cast<const bf16x8*>(
                    Ws + rb * 64 + (((ks * 4 + lq) ^ (lr & 7)) * 8));
            }
        }
        #pragma unroll
        for (int ks = 0; ks < 2; ++ks)
            #pragma unroll
            for (int fm = 0; fm < 4; ++fm)
                #pragma unroll
                for (int fn = 0; fn < FN; ++fn)
                    acc[fm][fn] = mfma16(af[ks][fm], wf[ks][fn], acc[fm][fn]);
    }

    #pragma unroll
    for (int fm = 0; fm < 4; ++fm) {
        #pragma unroll
        for (int fn = 0; fn < FN; ++fn) {
            int row = bm + wm * 64 + fm * 16 + lq * 4;
            int col = bn + wn * (FN * 16) + fn * 16 + lr;
            float bv = bias[col];
            #pragma unroll
            for (int r = 0; r < 4; ++r) {
                float v = acc[fm][fn][r] + bv;
                if (BF16_OUT)
                    ((bf16*)Cout)[(size_t)(row + r) * N + col] = (bf16)v;
                else
                    ((float*)Cout)[(size_t)(row + r) * N + col] = v;
            }
        }
    }
}

// ---------------- V transpose: qkv V-part -> vT[b*12+h][d=64][t=2048] ----------
__global__ __launch_bounds__(256) void k_transV(const bf16* __restrict__ qkv,
                                                bf16* __restrict__ vT) {
    const int g = blockIdx.x;
    const int bh = g >> 4, tc = g & 15;
    const int h = bh % 12, b = bh / 12;
    const int t0 = tc * 128;
    __shared__ bf16 Lt[128][68];
    const bf16* src = qkv + (size_t)(b * 2048 + t0) * 2304 + 1536 + h * 64;
    const int tid = threadIdx.x;
    #pragma unroll
    for (int ii = 0; ii < 4; ++ii) {
        int tt = ii * 32 + (tid >> 3);
        int ch = tid & 7;
        bf16x8 v = *reinterpret_cast<const bf16x8*>(src + (size_t)tt * 2304 + ch * 8);
        union { bf16x8 v8; bf16x4 h4[2]; } u; u.v8 = v;
        *reinterpret_cast<bf16x4*>(&Lt[tt][ch * 8])     = u.h4[0];
        *reinterpret_cast<bf16x4*>(&Lt[tt][ch * 8 + 4]) = u.h4[1];
    }
    __syncthreads();
    bf16* dst = vT + (size_t)bh * 64 * 2048 + t0;
    const int d = tid >> 2;
    #pragma unroll
    for (int ii = 0; ii < 4; ++ii) {
        int tch = ii * 4 + (tid & 3);
        bf16x8 v;
        #pragma unroll
        for (int e = 0; e < 8; ++e) v[e] = Lt[tch * 8 + e][d];
        *reinterpret_cast<bf16x8*>(&dst[(size_t)d * 2048 + tch * 8]) = v;
    }
}

// ---------------- causal flash attention (kv-split across waves) --------------
// Wave w = (qh = w>>1, hv = w&1): q-half qh (32 rows), kv-half hv (32 of 64).
// K: 3-buffer 2-ahead; V: 2-buffer 1-ahead; steady vmcnt(2); LDS 40KB, 4/CU.
#define CLOG2E 1.02014439f   // (1/sqrt(2)) * log2(e)

__global__ __launch_bounds__(256, 4) void k_flash_attn(
        const bf16* __restrict__ qkv, const bf16* __restrict__ vT,
        bf16* __restrict__ att, float* __restrict__ part, int mode) {
    __shared__ bf16 Ks[3][4096];   // [kv][d], chunk j of row holds src chunk j^(row&7)
    __shared__ bf16 VTs[2][4096];  // [d][kv], same swizzle

    const int tid = threadIdx.x;
    const int l = tid & 63, w = tid >> 6;
    const int lr = l & 15, lq = l >> 4;
    const int qh = w >> 1, hv = w & 1;

    const int bid = blockIdx.x;
    int qb, h, b, jt0, jt1, slot;
    bool dopart;
    if (mode) {
        int bh = bid % 24, idx = bid / 24;
        h = bh % 12; b = bh / 12;
        if (idx < 16)      { qb = 16 + idx;  jt0 = 0;  jt1 = 16;     dopart = true;  slot = (bh * 16 + idx) * 2; }
        else if (idx < 32) { qb = 47 - idx;  jt0 = 16; jt1 = qb + 1; dopart = true;  slot = (bh * 16 + (qb - 16)) * 2 + 1; }
        else               { qb = 47 - idx;  jt0 = 0;  jt1 = qb + 1; dopart = false; slot = 0; }
    } else {
        const int s = bid >> 8, i = (bid >> 3) & 31, t7 = bid & 7;
        if (s == 0)      qb = i;
        else if (s == 2) qb = (i + 16) & 31;
        else             qb = (i < 8) ? (31 - 2 * i) : (i < 16) ? (30 - 2 * i)
                           : (i < 24) ? (62 - 2 * i) : (63 - 2 * i);
        const int hb = s * 8 + t7;
        h = hb % 12; b = hb / 12;
        jt0 = 0; jt1 = qb + 1; dopart = false; slot = 0;
    }

    const bf16* Qp  = qkv + (size_t)b * 2048 * 2304 + h * 64;
    const bf16* Kp  = Qp + 768;
    const bf16* Vtp = vT + (size_t)(b * 12 + h) * 64 * 2048;  // [d][t]

    // Q rows for this wave: qb*64 + qh*32 + qg*16 + lr
    bf16x8 qf[2][2];
    #pragma unroll
    for (int qg = 0; qg < 2; ++qg)
        #pragma unroll
        for (int ks = 0; ks < 2; ++ks)
            qf[qg][ks] = *reinterpret_cast<const bf16x8*>(
                Qp + (size_t)(qb * 64 + qh * 32 + qg * 16 + lr) * 2304 + ks * 32 + lq * 8);

    f32x4 o[2][4] = {};
    float lsum0 = 0.f, lsum1 = 0.f;

    auto stageK = [&](int buf, int kv0) {
        #pragma unroll
        for (int ii = 0; ii < 2; ++ii) {
            int c = tid + ii * 256;
            int row = c >> 3, j = c & 7;
            gload_lds16(Kp + (size_t)(kv0 + row) * 2304 + ((j ^ (row & 7)) * 8),
                        &Ks[buf][c * 8]);
        }
    };
    auto stageV = [&](int buf, int kv0) {
        #pragma unroll
        for (int ii = 0; ii < 2; ++ii) {
            int c = tid + ii * 256;
            int row = c >> 3, j = c & 7;       // row = d, chunks along kv
            gload_lds16(Vtp + (size_t)row * 2048 + kv0 + ((j ^ (row & 7)) * 8),
                        &VTs[buf][c * 8]);
        }
    };

    // prologue: K(0), V(0), K(1); wait K0+V0 (leave K1 in flight)
    stageK(0, jt0 * 64);
    stageV(0, jt0 * 64);
    const bool two = (jt1 > jt0 + 1);
    if (two) stageK(1, jt0 * 64 + 64);
    if (two) asm volatile("s_waitcnt vmcnt(2)" ::: "memory");
    else     asm volatile("s_waitcnt vmcnt(0)" ::: "memory");
    __builtin_amdgcn_s_barrier();
    asm volatile("" ::: "memory");

    const int rsw = lr & 7;

    for (int jt = jt0; jt < jt1; ++jt) {
        const int curK = (jt - jt0) % 3;
        const int curV = (jt - jt0) & 1;
        const int kv0 = jt * 64;
        if (jt + 1 < jt1) stageV(curV ^ 1, kv0 + 64);            // V: 1-ahead
        if (jt + 2 < jt1) stageK((jt + 2 - jt0) % 3, kv0 + 128); // K: 2-ahead

        const bool diag = (jt == qb);
        float p[2][2][4];   // [t'][qg][r]; kv = hv*32 + t'*16 + lq*4 + r; q col = lr
        __builtin_amdgcn_s_setprio(1);
        #pragma unroll
        for (int tp = 0; tp < 2; ++tp) {
            const int row = hv * 32 + tp * 16 + lr;
            bf16x8 kf0 = *reinterpret_cast<const bf16x8*>(
                &Ks[curK][row * 64 + ((lq ^ rsw) * 8)]);
            bf16x8 kf1 = *reinterpret_cast<const bf16x8*>(
                &Ks[curK][row * 64 + (((4 + lq) ^ rsw) * 8)]);
            #pragma unroll
            for (int qg = 0; qg < 2; ++qg) {
                f32x4 s = {0.f, 0.f, 0.f, 0.f};
                s = mfma16(kf0, qf[qg][0], s);
                s = mfma16(kf1, qf[qg][1], s);
                #pragma unroll
                for (int r = 0; r < 4; ++r)
                    p[tp][qg][r] = __builtin_amdgcn_exp2f(s[r] * CLOG2E);
            }
        }
        __builtin_amdgcn_s_setprio(0);
        if (diag) {            // wave-uniform: mask only on the diagonal tile
            #pragma unroll
            for (int tp = 0; tp < 2; ++tp)
                #pragma unroll
                for (int qg = 0; qg < 2; ++qg)
                    #pragma unroll
                    for (int r = 0; r < 4; ++r)
                        if (hv * 32 + tp * 16 + lq * 4 + r > qh * 32 + qg * 16 + lr)
                            p[tp][qg][r] = 0.f;
        }
        {   // tree-reduced tile sums per q-group
            float a0 = (p[0][0][0] + p[0][0][1]) + (p[0][0][2] + p[0][0][3]);
            float a1 = (p[1][0][0] + p[1][0][1]) + (p[1][0][2] + p[1][0][3]);
            lsum0 += a0 + a1;
            float b0 = (p[0][1][0] + p[0][1][1]) + (p[0][1][2] + p[0][1][3]);
            float b1 = (p[1][1][0] + p[1][1][1]) + (p[1][1][2] + p[1][1][3]);
            lsum1 += b0 + b1;
        }

        // T12 relabeled: per qg, p[t'][qg][*] -> pa[qg] = P[q=lr][kv_local=lq*8+e]
        bf16x8 pa[2];
        #pragma unroll
        for (int qg = 0; qg < 2; ++qg) {
            unsigned A0, B0, A1, B1;
            asm("v_cvt_pk_bf16_f32 %0, %1, %2" : "=v"(A0) : "v"(p[0][qg][0]), "v"(p[0][qg][1]));
            asm("v_cvt_pk_bf16_f32 %0, %1, %2" : "=v"(A1) : "v"(p[0][qg][2]), "v"(p[0][qg][3]));
            asm("v_cvt_pk_bf16_f32 %0, %1, %2" : "=v"(B0) : "v"(p[1][qg][0]), "v"(p[1][qg][1]));
            asm("v_cvt_pk_bf16_f32 %0, %1, %2" : "=v"(B1) : "v"(p[1][qg][2]), "v"(p[1][qg][3]));
            asm volatile("v_permlane32_swap_b32 %0, %1" : "+v"(A0), "+v"(B0));
            asm volatile("v_permlane16_swap_b32 %0, %1" : "+v"(A0), "+v"(B0));
            asm volatile("v_permlane32_swap_b32 %0, %1" : "+v"(A1), "+v"(B1));
            asm volatile("v_permlane16_swap_b32 %0, %1" : "+v"(A1), "+v"(B1));
            union { unsigned u[4]; bf16x8 v8; } pk_;
            pk_.u[0] = A0; pk_.u[1] = A1; pk_.u[2] = B0; pk_.u[3] = B1;
            pa[qg] = pk_.v8;
        }

        __builtin_amdgcn_s_setprio(1);
        #pragma unroll
        for (int db = 0; db < 4; ++db) {
            const int row = db * 16 + lr;
            bf16x8 vf = *reinterpret_cast<const bf16x8*>(
                &VTs[curV][row * 64 + (((hv * 4 + lq) ^ rsw) * 8)]);
            o[0][db] = mfma16(pa[0], vf, o[0][db]);
            o[1][db] = mfma16(pa[1], vf, o[1][db]);
        }
        __builtin_amdgcn_s_setprio(0);

        // counted wait: K(j+1)+V(j+1) complete; K(j+2) stays in flight
        if (jt + 1 < jt1) {
            if (jt + 2 < jt1) asm volatile("s_waitcnt vmcnt(2)" ::: "memory");
            else              asm volatile("s_waitcnt vmcnt(0)" ::: "memory");
        }
        __builtin_amdgcn_s_barrier();
        asm volatile("" ::: "memory");
    }

    // wave-level row sums (over this wave's kv-half) across the 4 lq groups
    lsum0 += __shfl_xor(lsum0, 16); lsum0 += __shfl_xor(lsum0, 32);
    lsum1 += __shfl_xor(lsum1, 16); lsum1 += __shfl_xor(lsum1, 32);

    // cross-pair combine via reused Ks LDS: hv=1 writes, hv=0 adds + stores.
    {
        float* xf = (float*)&Ks[0][0];     // 2 regions x 64 lanes x 34 f32 = 17408 B
        float* rg = xf + (size_t)(qh * 64 + l) * 34;
        if (hv == 1) {
            #pragma unroll
            for (int qg = 0; qg < 2; ++qg)
                #pragma unroll
                for (int db = 0; db < 4; ++db)
                    #pragma unroll
                    for (int r = 0; r < 4; ++r)
                        rg[qg * 16 + db * 4 + r] = o[qg][db][r];
            rg[32] = lsum0; rg[33] = lsum1;
        }
        __syncthreads();
        if (hv == 0) {
            #pragma unroll
            for (int qg = 0; qg < 2; ++qg)
                #pragma unroll
                for (int db = 0; db < 4; ++db)
                    #pragma unroll
                    for (int r = 0; r < 4; ++r)
                        o[qg][db][r] += rg[qg * 16 + db * 4 + r];
            lsum0 += rg[32]; lsum1 += rg[33];

            if (dopart) {
                float* pb = part + (size_t)slot * 4160;
                #pragma unroll
                for (int qg = 0; qg < 2; ++qg) {
                    #pragma unroll
                    for (int db = 0; db < 4; ++db)
                        #pragma unroll
                        for (int r = 0; r < 4; ++r)
                            pb[(qh * 32 + qg * 16 + lq * 4 + r) * 64 + db * 16 + lr] = o[qg][db][r];
                }
                if (lq == 0) {
                    pb[4096 + qh * 32 + lr]      = lsum0;
                    pb[4096 + qh * 32 + 16 + lr] = lsum1;
                }
            } else {
                float inv0[4], inv1[4];
                #pragma unroll
                for (int r = 0; r < 4; ++r) {
                    inv0[r] = 1.0f / __shfl(lsum0, lq * 4 + r);
                    inv1[r] = 1.0f / __shfl(lsum1, lq * 4 + r);
                }
                #pragma unroll
                for (int db = 0; db < 4; ++db)
                    #pragma unroll
                    for (int r = 0; r < 4; ++r) {
                        int q0 = qb * 64 + qh * 32 + lq * 4 + r;
                        att[(size_t)(b * 2048 + q0) * 768 + h * 64 + db * 16 + lr] =
                            (bf16)(o[0][db][r] * inv0[r]);
                        att[(size_t)(b * 2048 + q0 + 16) * 768 + h * 64 + db * 16 + lr] =
                            (bf16)(o[1][db][r] * inv1[r]);
                    }
            }
        }
    }
}

// ---------------- combine split-KV partials ----------------
__global__ __launch_bounds__(256) void k_attn_reduce(
        const float* __restrict__ part, bf16* __restrict__ att) {
    int g = blockIdx.x;                 // 384 = 24 bh * 16 qb
    int bh = g / 16, q16 = g % 16, qb = 16 + q16;
    int h = bh % 12, b = bh / 12;
    const float* p0 = part + (size_t)((bh * 16 + q16) * 2) * 4160;
    const float* p1 = p0 + 4160;
    for (int e = threadIdx.x; e < 4096; e += 256) {
        int row = e >> 6, col = e & 63;
        float O = p0[e] + p1[e];
        float L = p0[4096 + row] + p1[4096 + row];
        att[(size_t)(b * 2048 + qb * 64 + row) * 768 + h * 64 + col] = (bf16)(O / L);
    }
}

// ---------------- launch ----------------
extern "C" void kernel_launch(void* const* d_in, const int* in_sizes, int n_in,
                              void* d_out, int out_size, void* d_ws, size_t ws_size,
                              hipStream_t stream) {
    const float* x      = (const float*)d_in[0];
    const float* w_attn = (const float*)d_in[1];
    const float* b_attn = (const float*)d_in[2];
    const float* w_proj = (const float*)d_in[3];
    const float* b_proj = (const float*)d_in[4];

    char* ws = (char*)d_ws;
    bf16* xb   = (bf16*)(ws + 0);          // 4096x768   = 6291456 B (dead after gemm1)
    bf16* vT   = (bf16*)(ws + 0);          // 24x64x2048 = 6291456 B (overlaps xb)
    bf16* wab  = (bf16*)(ws + 6291456);    // 2304x768   = 3538944 B
    bf16* wpb  = (bf16*)(ws + 9830400);    //  768x768   = 1179648 B
    bf16* qkv  = (bf16*)(ws + 11010048);   // 4096x2304  = 18874368 B
    bf16* att  = (bf16*)(ws + 29884416);   // 4096x768   = 6291456 B
    float* part = (float*)(ws + 36175872); // 768 slots x 4160 f32 = 12779520 B
    const unsigned long long WS_NEEDED = 36175872ull + 12779520ull;  // proven available (R5)

    k_cast3<<<2048, 256, 0, stream>>>(x, w_attn, w_proj, xb, wab, wpb);

    // gemm1: 576 CTAs (576 % 8 == 0 -> bijective XCD swizzle)
    k_gemm_bt<128, true><<<576, 256, 0, stream>>>(xb, wab, b_attn, qkv, 4096, 2304, 768);

    k_transV<<<384, 256, 0, stream>>>(qkv, vT);

    if (ws_size >= WS_NEEDED) {
        k_flash_attn<<<1152, 256, 0, stream>>>(qkv, vT, att, part, 1);
        k_attn_reduce<<<384, 256, 0, stream>>>(part, att);
    } else {
        k_flash_attn<<<768, 256, 0, stream>>>(qkv, vT, att, part, 0);
    }

    // gemm2: 384 CTAs (384 % 8 == 0)
    k_gemm_bt<64, false><<<384, 256, 0, stream>>>(att, wpb, b_proj, d_out, 4096, 768, 768);
}